// Round 11
// baseline (382.265 us; speedup 1.0000x reference)
//
#include <hip/hip_runtime.h>

#define IN_F 256
#define HID1 128
#define HID2 64

typedef __bf16 bf16x8 __attribute__((ext_vector_type(8)));
typedef float f32x4 __attribute__((ext_vector_type(4)));
typedef unsigned short ushort8 __attribute__((ext_vector_type(8)));
typedef unsigned short ushort4v __attribute__((ext_vector_type(4)));
typedef unsigned long long u64;

__device__ inline unsigned short f2bf(float f) {
    unsigned int u = __float_as_uint(f);
    u += 0x7fffu + ((u >> 16) & 1u);   // round-to-nearest-even
    return (unsigned short)(u >> 16);
}
__device__ inline float bf2f(unsigned short u) {
    return __uint_as_float(((unsigned int)u) << 16);
}

// ---------------- index-format detection ----------------
__global__ void detect_kernel(const int* __restrict__ e, long long nOdd, int* flag) {
    long long stride = (long long)gridDim.x * blockDim.x;
    for (long long i = (long long)blockIdx.x * blockDim.x + threadIdx.x; i < nOdd; i += stride) {
        if (e[2 * i + 1] != 0) { *flag = 1; return; }
    }
}

__device__ inline int edge_src(const void* e, const int is32, long long i, int E) {
    return is32 ? ((const int*)e)[i] : (int)((const long long*)e)[i];
}
__device__ inline int edge_dst(const void* e, const int is32, long long i, int E) {
    return is32 ? ((const int*)e)[E + i] : (int)((const long long*)e)[E + i];
}

// ---------------- degree count ----------------
__global__ void indeg_kernel(const void* __restrict__ e, const int* __restrict__ flag,
                             int* __restrict__ cnt, int N, int E) {
    const int is32 = *flag;
    long long stride = (long long)gridDim.x * blockDim.x;
    for (long long i = (long long)blockIdx.x * blockDim.x + threadIdx.x; i < E; i += stride) {
        int d = edge_dst(e, is32, i, E);
        if ((unsigned)d < (unsigned)N) atomicAdd(&cnt[d], 1);
    }
}

__global__ void dinv_kernel(const int* __restrict__ cnt, float* __restrict__ dinv, int N) {
    int i = blockIdx.x * blockDim.x + threadIdx.x;
    if (i < N) dinv[i] = rsqrtf((float)(cnt[i] + 1));
}

// ---------------- exclusive scan ----------------
__global__ __launch_bounds__(256) void scan1_kernel(const int* __restrict__ cnt,
                                                    int* __restrict__ excl,
                                                    int* __restrict__ bsum, int N) {
    __shared__ int wsums[4];
    __shared__ int wpre[4];
    const int t = threadIdx.x;
    const int base = blockIdx.x * 2048 + t * 8;
    int v[8];
    int s = 0;
#pragma unroll
    for (int j = 0; j < 8; j++) {
        v[j] = (base + j < N) ? cnt[base + j] : 0;
        s += v[j];
    }
    const int lane = t & 63;
    int x = s;
#pragma unroll
    for (int off = 1; off < 64; off <<= 1) {
        int y = __shfl_up(x, off, 64);
        if (lane >= off) x += y;
    }
    if (lane == 63) wsums[t >> 6] = x;
    __syncthreads();
    if (t == 0) {
        int r = 0;
        for (int w = 0; w < 4; w++) { wpre[w] = r; r += wsums[w]; }
    }
    __syncthreads();
    int run = wpre[t >> 6] + x - s;
#pragma unroll
    for (int j = 0; j < 8; j++) {
        if (base + j < N) excl[base + j] = run;
        run += v[j];
    }
    if (t == 255) bsum[blockIdx.x] = wpre[3] + wsums[3];
}

__global__ void scan2_kernel(int* bsum, int NB) {
    if (threadIdx.x == 0 && blockIdx.x == 0) {
        int r = 0;
        for (int i = 0; i < NB; i++) { int t = bsum[i]; bsum[i] = r; r += t; }
        bsum[NB] = r;
    }
}

__global__ void scan3_kernel(const int* __restrict__ excl, const int* __restrict__ bsum,
                             int* __restrict__ rowptr, int* __restrict__ cursor, int N) {
    int i = blockIdx.x * blockDim.x + threadIdx.x;
    if (i < N) {
        int rp = excl[i] + bsum[i >> 11];
        rowptr[i] = rp;
        cursor[i] = rp;
    } else if (i == N) {
        rowptr[N] = bsum[(N + 2047) >> 11];
    }
}

// ---------------- CSR fill: 8B atomicExch per edge {dinv(src) | src} ----------
// Plain scatter stores thrash per-XCD L2 lines (WRITE_SIZE = E*64B). Device-scope
// atomics execute at the memory-side coherent point (indeg evidence) -> no line
// allocate/evict per write.
__global__ void fill_kernel(const void* __restrict__ e, const int* __restrict__ flag,
                            const float* __restrict__ dinv, int* __restrict__ cursor,
                            u64* __restrict__ cw, int N, int E) {
    const int is32 = *flag;
    long long stride = (long long)gridDim.x * blockDim.x;
    for (long long i = (long long)blockIdx.x * blockDim.x + threadIdx.x; i < E; i += stride) {
        int s = edge_src(e, is32, i, E);
        int d = edge_dst(e, is32, i, E);
        if ((unsigned)s >= (unsigned)N || (unsigned)d >= (unsigned)N) continue;
        int pos = atomicAdd(&cursor[d], 1);
        u64 v = ((u64)(unsigned int)__float_as_uint(dinv[s]) << 32) | (unsigned int)s;
        atomicExch(&cw[pos], v);
    }
}

// ---------------- W1^T bf16 prep: Wbt[col][k] = bf16(W[k][col]) ----------------
__global__ void w1bt_kernel(const float* __restrict__ W, unsigned short* __restrict__ Wbt) {
    int t = blockIdx.x * 256 + threadIdx.x;
    if (t >= HID1 * IN_F) return;
    int c = t >> 8;              // col 0..127
    int k = t & 255;             // k 0..255
    Wbt[t] = f2bf(W[k * HID1 + c]);
}

// ---------------- GEMM1 MFMA: h1b[N,128](bf16) = x[N,256] @ W1[256,128] ----------------
__global__ __launch_bounds__(256) void gemm1_mfma_kernel(const float* __restrict__ x,
                                                         const unsigned short* __restrict__ Wbt,
                                                         unsigned short* __restrict__ hb, int N) {
    __shared__ unsigned short As[64 * 64];    // [row][k] swizzled, 8 KB
    __shared__ unsigned short Bs[128 * 64];   // [col][k] swizzled, 16 KB
    const int t = threadIdx.x;
    const int w = t >> 6;          // wave 0..3 -> cols w*32..+31
    const int l = t & 63;
    const int lrow = l & 15;
    const int g = l >> 4;          // k-block 0..3
    const int row0 = blockIdx.x * 64;

    f32x4 acc[4][2];
#pragma unroll
    for (int m = 0; m < 4; m++)
#pragma unroll
        for (int n = 0; n < 2; n++) acc[m][n] = (f32x4){0.f, 0.f, 0.f, 0.f};

    for (int kc = 0; kc < 4; kc++) {
        __syncthreads();
        // stage A: 64 rows x 64 k (f32 -> bf16)
#pragma unroll
        for (int it = 0; it < 2; it++) {
            int slot = it * 256 + t;
            int r = slot >> 3;
            int k0 = (slot & 7) * 8;
            int grow = row0 + r;
            float4 v0 = make_float4(0.f, 0.f, 0.f, 0.f), v1 = v0;
            if (grow < N) {
                const float* p = &x[(long long)grow * IN_F + kc * 64 + k0];
                v0 = *(const float4*)p;
                v1 = *(const float4*)(p + 4);
            }
            ushort8 u;
            u[0] = f2bf(v0.x); u[1] = f2bf(v0.y); u[2] = f2bf(v0.z); u[3] = f2bf(v0.w);
            u[4] = f2bf(v1.x); u[5] = f2bf(v1.y); u[6] = f2bf(v1.z); u[7] = f2bf(v1.w);
            *(ushort8*)&As[r * 64 + (k0 ^ ((r & 7) << 3))] = u;
        }
        // stage B: 128 cols x 64 k bf16 copy
#pragma unroll
        for (int it = 0; it < 4; it++) {
            int slot = it * 256 + t;
            int c = slot >> 3;
            int k0 = (slot & 7) * 8;
            ushort8 u = *(const ushort8*)&Wbt[c * IN_F + kc * 64 + k0];
            *(ushort8*)&Bs[c * 64 + (k0 ^ ((c & 7) << 3))] = u;
        }
        __syncthreads();
#pragma unroll
        for (int ks = 0; ks < 2; ks++) {
            int kk = ks * 32 + g * 8;
            bf16x8 af[4], bfr[2];
#pragma unroll
            for (int m = 0; m < 4; m++) {
                int r = m * 16 + lrow;
                af[m] = *(bf16x8*)&As[r * 64 + (kk ^ ((r & 7) << 3))];
            }
#pragma unroll
            for (int n = 0; n < 2; n++) {
                int c = w * 32 + n * 16 + lrow;
                bfr[n] = *(bf16x8*)&Bs[c * 64 + (kk ^ ((c & 7) << 3))];
            }
#pragma unroll
            for (int m = 0; m < 4; m++)
#pragma unroll
                for (int n = 0; n < 2; n++)
                    acc[m][n] = __builtin_amdgcn_mfma_f32_16x16x32_bf16(af[m], bfr[n], acc[m][n], 0, 0, 0);
        }
    }
    // epilogue -> bf16: C col = lane&15, row = (lane>>4)*4 + j
#pragma unroll
    for (int m = 0; m < 4; m++) {
        int rbase = row0 + m * 16 + g * 4;
#pragma unroll
        for (int j = 0; j < 4; j++) {
            int grow = rbase + j;
            if (grow < N) {
#pragma unroll
                for (int n = 0; n < 2; n++)
                    hb[(long long)grow * HID1 + w * 32 + n * 16 + lrow] = f2bf(acc[m][n][j]);
            }
        }
    }
}

// ---------------- GEMM 2: h2b[N,64](bf16) = relu(agg1[N,128]) @ W2[128,64] ----------------
__global__ __launch_bounds__(256) void gemm2_kernel(const float* __restrict__ a_in,
                                                    const float* __restrict__ W,
                                                    unsigned short* __restrict__ hb, int N) {
    __shared__ float xs[64][65];
    __shared__ float4 wt[64 * 16];
    const int t = threadIdx.x;
    const int row0 = blockIdx.x * 64;
    const int rg = t >> 4;
    const int c4 = t & 15;

    float4 acc[4];
#pragma unroll
    for (int i = 0; i < 4; i++) acc[i] = make_float4(0.f, 0.f, 0.f, 0.f);

    for (int kc = 0; kc < 2; kc++) {
        __syncthreads();
        {
            int rr = t >> 4;
            int cc = t & 15;
#pragma unroll
            for (int it = 0; it < 4; it++) {
                int r = it * 16 + rr;
                int grow = row0 + r;
                float4 v = make_float4(0.f, 0.f, 0.f, 0.f);
                if (grow < N)
                    v = *(const float4*)&a_in[(long long)grow * HID1 + kc * 64 + cc * 4];
                xs[r][cc * 4 + 0] = fmaxf(v.x, 0.f); xs[r][cc * 4 + 1] = fmaxf(v.y, 0.f);
                xs[r][cc * 4 + 2] = fmaxf(v.z, 0.f); xs[r][cc * 4 + 3] = fmaxf(v.w, 0.f);
            }
        }
        {
#pragma unroll
            for (int it = 0; it < 4; it++) {
                int f = it * 256 + t;
                int wr = f >> 4, wc = f & 15;
                wt[wr * 16 + wc] = *(const float4*)&W[(kc * 64 + wr) * HID2 + wc * 4];
            }
        }
        __syncthreads();
#pragma unroll 16
        for (int k = 0; k < 64; k++) {
            float4 w4 = wt[k * 16 + c4];
#pragma unroll
            for (int i = 0; i < 4; i++) {
                float a = xs[rg * 4 + i][k];
                acc[i].x += a * w4.x; acc[i].y += a * w4.y;
                acc[i].z += a * w4.z; acc[i].w += a * w4.w;
            }
        }
    }
#pragma unroll
    for (int i = 0; i < 4; i++) {
        int grow = row0 + rg * 4 + i;
        if (grow < N) {
            ushort4v u;
            u[0] = f2bf(acc[i].x); u[1] = f2bf(acc[i].y);
            u[2] = f2bf(acc[i].z); u[3] = f2bf(acc[i].w);
            *(ushort4v*)&hb[(long long)grow * HID2 + c4 * 4] = u;
        }
    }
}

// ---------------- CSR gather (bf16 features, packed u64 edges) ----------------
template <int G>   // threads per node; each thread owns 8 bf16 columns
__global__ __launch_bounds__(256) void gather_bf16_kernel(const unsigned short* __restrict__ hb,
                                                          const float* __restrict__ bias,
                                                          const float* __restrict__ dinv,
                                                          const int* __restrict__ rowptr,
                                                          const u64* __restrict__ cw,
                                                          float* __restrict__ out, int N) {
    long long tid = (long long)blockIdx.x * 256 + threadIdx.x;
    int node = (int)(tid / G);
    int g = (int)(tid % G);
    if (node >= N) return;
    const ushort8* h8 = (const ushort8*)hb;
    float di = dinv[node];
    ushort8 hv = h8[(long long)node * G + g];
    float sum[8];
#pragma unroll
    for (int j = 0; j < 8; j++) sum[j] = di * bf2f(hv[j]);
    int p0 = rowptr[node], p1 = rowptr[node + 1];
    int p = p0;
    for (; p + 1 < p1; p += 2) {
        u64 c0 = cw[p], c1 = cw[p + 1];
        int s0 = (int)(unsigned int)c0, s1 = (int)(unsigned int)c1;
        float w0 = __uint_as_float((unsigned int)(c0 >> 32));
        float w1 = __uint_as_float((unsigned int)(c1 >> 32));
        ushort8 v0 = h8[(long long)s0 * G + g];
        ushort8 v1 = h8[(long long)s1 * G + g];
#pragma unroll
        for (int j = 0; j < 8; j++)
            sum[j] += w0 * bf2f(v0[j]) + w1 * bf2f(v1[j]);
    }
    if (p < p1) {
        u64 c0 = cw[p];
        int s0 = (int)(unsigned int)c0;
        float w0 = __uint_as_float((unsigned int)(c0 >> 32));
        ushort8 v0 = h8[(long long)s0 * G + g];
#pragma unroll
        for (int j = 0; j < 8; j++) sum[j] += w0 * bf2f(v0[j]);
    }
    float4 b0 = ((const float4*)bias)[g * 2];
    float4 b1 = ((const float4*)bias)[g * 2 + 1];
    float4 o0, o1;
    o0.x = b0.x + di * sum[0]; o0.y = b0.y + di * sum[1];
    o0.z = b0.z + di * sum[2]; o0.w = b0.w + di * sum[3];
    o1.x = b1.x + di * sum[4]; o1.y = b1.y + di * sum[5];
    o1.z = b1.z + di * sum[6]; o1.w = b1.w + di * sum[7];
    float4* op = (float4*)&out[((long long)node * G + g) * 8];
    op[0] = o0;
    op[1] = o1;
}

extern "C" void kernel_launch(void* const* d_in, const int* in_sizes, int n_in,
                              void* d_out, int out_size, void* d_ws, size_t ws_size,
                              hipStream_t stream) {
    const float* x  = (const float*)d_in[0];
    const void*  ei = d_in[1];
    const float* W1 = (const float*)d_in[2];
    const float* b1 = (const float*)d_in[3];
    const float* W2 = (const float*)d_in[4];
    const float* b2 = (const float*)d_in[5];
    float* out = (float*)d_out;

    const int N = in_sizes[0] / IN_F;          // 100000
    const int E = in_sizes[1] / 2;             // 1600000
    const int NB = (N + 2047) / 2048;

    char* ws = (char*)d_ws;
    size_t off = 0;
    auto alloc = [&](size_t bytes) -> char* {
        char* p = ws + off;
        off = (off + bytes + 255) & ~(size_t)255;
        return p;
    };
    int*   flag   = (int*)alloc(4);
    int*   cnt    = (int*)alloc((size_t)N * 4);
    float* dinv   = (float*)alloc((size_t)N * 4);
    int*   rowptr = (int*)alloc((size_t)(N + 1) * 4);
    int*   cursor = (int*)alloc((size_t)N * 4);
    int*   excl   = (int*)alloc((size_t)N * 4);
    int*   bsum   = (int*)alloc((size_t)(NB + 1) * 4);
    u64*   cw     = (u64*)alloc((size_t)E * 8);
    unsigned short* w1bt = (unsigned short*)alloc((size_t)HID1 * IN_F * 2);
    unsigned short* h1b  = (unsigned short*)alloc((size_t)N * HID1 * 2);  // bf16
    float* agg1   = (float*)alloc((size_t)N * HID1 * 4);
    unsigned short* h2b  = (unsigned short*)alloc((size_t)N * HID2 * 2);  // bf16

    hipMemsetAsync(flag, 0, sizeof(int), stream);
    hipMemsetAsync(cnt, 0, (size_t)N * 4, stream);

    detect_kernel<<<1024, 256, 0, stream>>>((const int*)ei, (long long)E, flag);
    indeg_kernel<<<2048, 256, 0, stream>>>(ei, flag, cnt, N, E);
    dinv_kernel<<<(N + 255) / 256, 256, 0, stream>>>(cnt, dinv, N);

    scan1_kernel<<<NB, 256, 0, stream>>>(cnt, excl, bsum, N);
    scan2_kernel<<<1, 64, 0, stream>>>(bsum, NB);
    scan3_kernel<<<(N + 256) / 256, 256, 0, stream>>>(excl, bsum, rowptr, cursor, N);

    fill_kernel<<<2048, 256, 0, stream>>>(ei, flag, dinv, cursor, cw, N, E);

    w1bt_kernel<<<(HID1 * IN_F + 255) / 256, 256, 0, stream>>>(W1, w1bt);

    // Layer 1: MFMA GEMM (bf16 out) -> bf16 gather (G = 128/8 = 16)
    gemm1_mfma_kernel<<<(N + 63) / 64, 256, 0, stream>>>(x, w1bt, h1b, N);
    gather_bf16_kernel<16><<<(int)(((long long)N * 16 + 255) / 256), 256, 0, stream>>>(
        h1b, b1, dinv, rowptr, cw, agg1, N);

    // Layer 2: f32 vector GEMM (relu fused, bf16 out) -> bf16 gather (G = 64/8 = 8)
    gemm2_kernel<<<(N + 63) / 64, 256, 0, stream>>>(agg1, W2, h2b, N);
    gather_bf16_kernel<8><<<(int)(((long long)N * 8 + 255) / 256), 256, 0, stream>>>(
        h2b, b2, dinv, rowptr, cw, out, N);
}

// Round 12
// 353.565 us; speedup vs baseline: 1.0812x; 1.0812x over previous
//
#include <hip/hip_runtime.h>

#define IN_F 256
#define HID1 128
#define HID2 64

typedef __bf16 bf16x8 __attribute__((ext_vector_type(8)));
typedef float f32x4 __attribute__((ext_vector_type(4)));
typedef unsigned short ushort8 __attribute__((ext_vector_type(8)));
typedef unsigned short ushort4v __attribute__((ext_vector_type(4)));
typedef unsigned long long u64;

__device__ inline unsigned short f2bf(float f) {
    unsigned int u = __float_as_uint(f);
    u += 0x7fffu + ((u >> 16) & 1u);   // round-to-nearest-even
    return (unsigned short)(u >> 16);
}
__device__ inline float bf2f(unsigned short u) {
    return __uint_as_float(((unsigned int)u) << 16);
}

// ---------------- index-format detection ----------------
__global__ void detect_kernel(const int* __restrict__ e, long long nOdd, int* flag) {
    long long stride = (long long)gridDim.x * blockDim.x;
    for (long long i = (long long)blockIdx.x * blockDim.x + threadIdx.x; i < nOdd; i += stride) {
        if (e[2 * i + 1] != 0) { *flag = 1; return; }
    }
}

__device__ inline int edge_src(const void* e, const int is32, long long i, int E) {
    return is32 ? ((const int*)e)[i] : (int)((const long long*)e)[i];
}
__device__ inline int edge_dst(const void* e, const int is32, long long i, int E) {
    return is32 ? ((const int*)e)[E + i] : (int)((const long long*)e)[E + i];
}

// ---------------- degree count ----------------
__global__ void indeg_kernel(const void* __restrict__ e, const int* __restrict__ flag,
                             int* __restrict__ cnt, int N, int E) {
    const int is32 = *flag;
    long long stride = (long long)gridDim.x * blockDim.x;
    for (long long i = (long long)blockIdx.x * blockDim.x + threadIdx.x; i < E; i += stride) {
        int d = edge_dst(e, is32, i, E);
        if ((unsigned)d < (unsigned)N) atomicAdd(&cnt[d], 1);
    }
}

__global__ void dinv_kernel(const int* __restrict__ cnt, float* __restrict__ dinv, int N) {
    int i = blockIdx.x * blockDim.x + threadIdx.x;
    if (i < N) dinv[i] = rsqrtf((float)(cnt[i] + 1));
}

// ---------------- exclusive scan ----------------
__global__ __launch_bounds__(256) void scan1_kernel(const int* __restrict__ cnt,
                                                    int* __restrict__ excl,
                                                    int* __restrict__ bsum, int N) {
    __shared__ int wsums[4];
    __shared__ int wpre[4];
    const int t = threadIdx.x;
    const int base = blockIdx.x * 2048 + t * 8;
    int v[8];
    int s = 0;
#pragma unroll
    for (int j = 0; j < 8; j++) {
        v[j] = (base + j < N) ? cnt[base + j] : 0;
        s += v[j];
    }
    const int lane = t & 63;
    int x = s;
#pragma unroll
    for (int off = 1; off < 64; off <<= 1) {
        int y = __shfl_up(x, off, 64);
        if (lane >= off) x += y;
    }
    if (lane == 63) wsums[t >> 6] = x;
    __syncthreads();
    if (t == 0) {
        int r = 0;
        for (int w = 0; w < 4; w++) { wpre[w] = r; r += wsums[w]; }
    }
    __syncthreads();
    int run = wpre[t >> 6] + x - s;
#pragma unroll
    for (int j = 0; j < 8; j++) {
        if (base + j < N) excl[base + j] = run;
        run += v[j];
    }
    if (t == 255) bsum[blockIdx.x] = wpre[3] + wsums[3];
}

__global__ void scan2_kernel(int* bsum, int NB) {
    if (threadIdx.x == 0 && blockIdx.x == 0) {
        int r = 0;
        for (int i = 0; i < NB; i++) { int t = bsum[i]; bsum[i] = r; r += t; }
        bsum[NB] = r;
    }
}

__global__ void scan3_kernel(const int* __restrict__ excl, const int* __restrict__ bsum,
                             int* __restrict__ rowptr, int* __restrict__ cursor, int N) {
    int i = blockIdx.x * blockDim.x + threadIdx.x;
    if (i < N) {
        int rp = excl[i] + bsum[i >> 11];
        rowptr[i] = rp;
        cursor[i] = rp;
    } else if (i == N) {
        rowptr[N] = bsum[(N + 2047) >> 11];
    }
}

// ---------------- CSR fill, dst-windowed: only edges with dst in [lo,hi) ----------
// Write region per pass = rowptr[lo]..rowptr[hi] (disjoint, ~3.2MB for W=4):
// stays L2-resident within the pass -> lines merge instead of bouncing between XCDs.
__global__ void fill_kernel(const void* __restrict__ e, const int* __restrict__ flag,
                            const float* __restrict__ dinv, int* __restrict__ cursor,
                            u64* __restrict__ cw, int E, int lo, int hi) {
    const int is32 = *flag;
    long long stride = (long long)gridDim.x * blockDim.x;
    for (long long i = (long long)blockIdx.x * blockDim.x + threadIdx.x; i < E; i += stride) {
        int d = edge_dst(e, is32, i, E);
        if (d < lo || d >= hi) continue;
        int s = edge_src(e, is32, i, E);
        if ((unsigned)s >= 0x80000000u) continue;
        int pos = atomicAdd(&cursor[d], 1);
        cw[pos] = ((u64)__float_as_uint(dinv[s]) << 32) | (unsigned int)s;
    }
}

// ---------------- W1^T bf16 prep: Wbt[col][k] = bf16(W[k][col]) ----------------
__global__ void w1bt_kernel(const float* __restrict__ W, unsigned short* __restrict__ Wbt) {
    int t = blockIdx.x * 256 + threadIdx.x;
    if (t >= HID1 * IN_F) return;
    int c = t >> 8;              // col 0..127
    int k = t & 255;             // k 0..255
    Wbt[t] = f2bf(W[k * HID1 + c]);
}

// ---------------- GEMM1 MFMA: h1b[N,128](bf16) = x[N,256] @ W1[256,128] ----------------
__global__ __launch_bounds__(256) void gemm1_mfma_kernel(const float* __restrict__ x,
                                                         const unsigned short* __restrict__ Wbt,
                                                         unsigned short* __restrict__ hb, int N) {
    __shared__ unsigned short As[64 * 64];    // [row][k] swizzled, 8 KB
    __shared__ unsigned short Bs[128 * 64];   // [col][k] swizzled, 16 KB
    const int t = threadIdx.x;
    const int w = t >> 6;          // wave 0..3 -> cols w*32..+31
    const int l = t & 63;
    const int lrow = l & 15;
    const int g = l >> 4;          // k-block 0..3
    const int row0 = blockIdx.x * 64;

    f32x4 acc[4][2];
#pragma unroll
    for (int m = 0; m < 4; m++)
#pragma unroll
        for (int n = 0; n < 2; n++) acc[m][n] = (f32x4){0.f, 0.f, 0.f, 0.f};

    for (int kc = 0; kc < 4; kc++) {
        __syncthreads();
        // stage A: 64 rows x 64 k (f32 -> bf16)
#pragma unroll
        for (int it = 0; it < 2; it++) {
            int slot = it * 256 + t;
            int r = slot >> 3;
            int k0 = (slot & 7) * 8;
            int grow = row0 + r;
            float4 v0 = make_float4(0.f, 0.f, 0.f, 0.f), v1 = v0;
            if (grow < N) {
                const float* p = &x[(long long)grow * IN_F + kc * 64 + k0];
                v0 = *(const float4*)p;
                v1 = *(const float4*)(p + 4);
            }
            ushort8 u;
            u[0] = f2bf(v0.x); u[1] = f2bf(v0.y); u[2] = f2bf(v0.z); u[3] = f2bf(v0.w);
            u[4] = f2bf(v1.x); u[5] = f2bf(v1.y); u[6] = f2bf(v1.z); u[7] = f2bf(v1.w);
            *(ushort8*)&As[r * 64 + (k0 ^ ((r & 7) << 3))] = u;
        }
        // stage B: 128 cols x 64 k bf16 copy
#pragma unroll
        for (int it = 0; it < 4; it++) {
            int slot = it * 256 + t;
            int c = slot >> 3;
            int k0 = (slot & 7) * 8;
            ushort8 u = *(const ushort8*)&Wbt[c * IN_F + kc * 64 + k0];
            *(ushort8*)&Bs[c * 64 + (k0 ^ ((c & 7) << 3))] = u;
        }
        __syncthreads();
#pragma unroll
        for (int ks = 0; ks < 2; ks++) {
            int kk = ks * 32 + g * 8;
            bf16x8 af[4], bfr[2];
#pragma unroll
            for (int m = 0; m < 4; m++) {
                int r = m * 16 + lrow;
                af[m] = *(bf16x8*)&As[r * 64 + (kk ^ ((r & 7) << 3))];
            }
#pragma unroll
            for (int n = 0; n < 2; n++) {
                int c = w * 32 + n * 16 + lrow;
                bfr[n] = *(bf16x8*)&Bs[c * 64 + (kk ^ ((c & 7) << 3))];
            }
#pragma unroll
            for (int m = 0; m < 4; m++)
#pragma unroll
                for (int n = 0; n < 2; n++)
                    acc[m][n] = __builtin_amdgcn_mfma_f32_16x16x32_bf16(af[m], bfr[n], acc[m][n], 0, 0, 0);
        }
    }
    // epilogue -> bf16: C col = lane&15, row = (lane>>4)*4 + j
#pragma unroll
    for (int m = 0; m < 4; m++) {
        int rbase = row0 + m * 16 + g * 4;
#pragma unroll
        for (int j = 0; j < 4; j++) {
            int grow = rbase + j;
            if (grow < N) {
#pragma unroll
                for (int n = 0; n < 2; n++)
                    hb[(long long)grow * HID1 + w * 32 + n * 16 + lrow] = f2bf(acc[m][n][j]);
            }
        }
    }
}

// ---------------- GEMM 2: h2b[N,64](bf16) = relu(agg1[N,128]) @ W2[128,64] ----------------
__global__ __launch_bounds__(256) void gemm2_kernel(const float* __restrict__ a_in,
                                                    const float* __restrict__ W,
                                                    unsigned short* __restrict__ hb, int N) {
    __shared__ float xs[64][65];
    __shared__ float4 wt[64 * 16];
    const int t = threadIdx.x;
    const int row0 = blockIdx.x * 64;
    const int rg = t >> 4;
    const int c4 = t & 15;

    float4 acc[4];
#pragma unroll
    for (int i = 0; i < 4; i++) acc[i] = make_float4(0.f, 0.f, 0.f, 0.f);

    for (int kc = 0; kc < 2; kc++) {
        __syncthreads();
        {
            int rr = t >> 4;
            int cc = t & 15;
#pragma unroll
            for (int it = 0; it < 4; it++) {
                int r = it * 16 + rr;
                int grow = row0 + r;
                float4 v = make_float4(0.f, 0.f, 0.f, 0.f);
                if (grow < N)
                    v = *(const float4*)&a_in[(long long)grow * HID1 + kc * 64 + cc * 4];
                xs[r][cc * 4 + 0] = fmaxf(v.x, 0.f); xs[r][cc * 4 + 1] = fmaxf(v.y, 0.f);
                xs[r][cc * 4 + 2] = fmaxf(v.z, 0.f); xs[r][cc * 4 + 3] = fmaxf(v.w, 0.f);
            }
        }
        {
#pragma unroll
            for (int it = 0; it < 4; it++) {
                int f = it * 256 + t;
                int wr = f >> 4, wc = f & 15;
                wt[wr * 16 + wc] = *(const float4*)&W[(kc * 64 + wr) * HID2 + wc * 4];
            }
        }
        __syncthreads();
#pragma unroll 16
        for (int k = 0; k < 64; k++) {
            float4 w4 = wt[k * 16 + c4];
#pragma unroll
            for (int i = 0; i < 4; i++) {
                float a = xs[rg * 4 + i][k];
                acc[i].x += a * w4.x; acc[i].y += a * w4.y;
                acc[i].z += a * w4.z; acc[i].w += a * w4.w;
            }
        }
    }
#pragma unroll
    for (int i = 0; i < 4; i++) {
        int grow = row0 + rg * 4 + i;
        if (grow < N) {
            ushort4v u;
            u[0] = f2bf(acc[i].x); u[1] = f2bf(acc[i].y);
            u[2] = f2bf(acc[i].z); u[3] = f2bf(acc[i].w);
            *(ushort4v*)&hb[(long long)grow * HID2 + c4 * 4] = u;
        }
    }
}

// ---------------- CSR gather (bf16 features, packed u64 edges) ----------------
template <int G>   // threads per node; each thread owns 8 bf16 columns
__global__ __launch_bounds__(256) void gather_bf16_kernel(const unsigned short* __restrict__ hb,
                                                          const float* __restrict__ bias,
                                                          const float* __restrict__ dinv,
                                                          const int* __restrict__ rowptr,
                                                          const u64* __restrict__ cw,
                                                          float* __restrict__ out, int N) {
    long long tid = (long long)blockIdx.x * 256 + threadIdx.x;
    int node = (int)(tid / G);
    int g = (int)(tid % G);
    if (node >= N) return;
    const ushort8* h8 = (const ushort8*)hb;
    float di = dinv[node];
    ushort8 hv = h8[(long long)node * G + g];
    float sum[8];
#pragma unroll
    for (int j = 0; j < 8; j++) sum[j] = di * bf2f(hv[j]);
    int p0 = rowptr[node], p1 = rowptr[node + 1];
    int p = p0;
    for (; p + 1 < p1; p += 2) {
        u64 c0 = cw[p], c1 = cw[p + 1];
        int s0 = (int)(unsigned int)c0, s1 = (int)(unsigned int)c1;
        float w0 = __uint_as_float((unsigned int)(c0 >> 32));
        float w1 = __uint_as_float((unsigned int)(c1 >> 32));
        ushort8 v0 = h8[(long long)s0 * G + g];
        ushort8 v1 = h8[(long long)s1 * G + g];
#pragma unroll
        for (int j = 0; j < 8; j++)
            sum[j] += w0 * bf2f(v0[j]) + w1 * bf2f(v1[j]);
    }
    if (p < p1) {
        u64 c0 = cw[p];
        int s0 = (int)(unsigned int)c0;
        float w0 = __uint_as_float((unsigned int)(c0 >> 32));
        ushort8 v0 = h8[(long long)s0 * G + g];
#pragma unroll
        for (int j = 0; j < 8; j++) sum[j] += w0 * bf2f(v0[j]);
    }
    float4 b0 = ((const float4*)bias)[g * 2];
    float4 b1 = ((const float4*)bias)[g * 2 + 1];
    float4 o0, o1;
    o0.x = b0.x + di * sum[0]; o0.y = b0.y + di * sum[1];
    o0.z = b0.z + di * sum[2]; o0.w = b0.w + di * sum[3];
    o1.x = b1.x + di * sum[4]; o1.y = b1.y + di * sum[5];
    o1.z = b1.z + di * sum[6]; o1.w = b1.w + di * sum[7];
    float4* op = (float4*)&out[((long long)node * G + g) * 8];
    op[0] = o0;
    op[1] = o1;
}

extern "C" void kernel_launch(void* const* d_in, const int* in_sizes, int n_in,
                              void* d_out, int out_size, void* d_ws, size_t ws_size,
                              hipStream_t stream) {
    const float* x  = (const float*)d_in[0];
    const void*  ei = d_in[1];
    const float* W1 = (const float*)d_in[2];
    const float* b1 = (const float*)d_in[3];
    const float* W2 = (const float*)d_in[4];
    const float* b2 = (const float*)d_in[5];
    float* out = (float*)d_out;

    const int N = in_sizes[0] / IN_F;          // 100000
    const int E = in_sizes[1] / 2;             // 1600000
    const int NB = (N + 2047) / 2048;

    char* ws = (char*)d_ws;
    size_t off = 0;
    auto alloc = [&](size_t bytes) -> char* {
        char* p = ws + off;
        off = (off + bytes + 255) & ~(size_t)255;
        return p;
    };
    int*   flag   = (int*)alloc(4);
    int*   cnt    = (int*)alloc((size_t)N * 4);
    float* dinv   = (float*)alloc((size_t)N * 4);
    int*   rowptr = (int*)alloc((size_t)(N + 1) * 4);
    int*   cursor = (int*)alloc((size_t)N * 4);
    int*   excl   = (int*)alloc((size_t)N * 4);
    int*   bsum   = (int*)alloc((size_t)(NB + 1) * 4);
    u64*   cw     = (u64*)alloc((size_t)E * 8);
    unsigned short* w1bt = (unsigned short*)alloc((size_t)HID1 * IN_F * 2);
    unsigned short* h1b  = (unsigned short*)alloc((size_t)N * HID1 * 2);  // bf16
    float* agg1   = (float*)alloc((size_t)N * HID1 * 4);
    unsigned short* h2b  = (unsigned short*)alloc((size_t)N * HID2 * 2);  // bf16

    hipMemsetAsync(flag, 0, sizeof(int), stream);
    hipMemsetAsync(cnt, 0, (size_t)N * 4, stream);

    detect_kernel<<<1024, 256, 0, stream>>>((const int*)ei, (long long)E, flag);
    indeg_kernel<<<2048, 256, 0, stream>>>(ei, flag, cnt, N, E);
    dinv_kernel<<<(N + 255) / 256, 256, 0, stream>>>(cnt, dinv, N);

    scan1_kernel<<<NB, 256, 0, stream>>>(cnt, excl, bsum, N);
    scan2_kernel<<<1, 64, 0, stream>>>(bsum, NB);
    scan3_kernel<<<(N + 256) / 256, 256, 0, stream>>>(excl, bsum, rowptr, cursor, N);

    // dst-windowed fill: 4 passes, each pass's write region (~E/4 * 8B) L2-resident
    const int W = 4;
    for (int p = 0; p < W; p++) {
        int lo = (int)((long long)N * p / W);
        int hi = (int)((long long)N * (p + 1) / W);
        fill_kernel<<<2048, 256, 0, stream>>>(ei, flag, dinv, cursor, cw, E, lo, hi);
    }

    w1bt_kernel<<<(HID1 * IN_F + 255) / 256, 256, 0, stream>>>(W1, w1bt);

    // Layer 1: MFMA GEMM (bf16 out) -> bf16 gather (G = 128/8 = 16)
    gemm1_mfma_kernel<<<(N + 63) / 64, 256, 0, stream>>>(x, w1bt, h1b, N);
    gather_bf16_kernel<16><<<(int)(((long long)N * 16 + 255) / 256), 256, 0, stream>>>(
        h1b, b1, dinv, rowptr, cw, agg1, N);

    // Layer 2: f32 vector GEMM (relu fused, bf16 out) -> bf16 gather (G = 64/8 = 8)
    gemm2_kernel<<<(N + 63) / 64, 256, 0, stream>>>(agg1, W2, h2b, N);
    gather_bf16_kernel<8><<<(int)(((long long)N * 8 + 255) / 256), 256, 0, stream>>>(
        h2b, b2, dinv, rowptr, cw, out, N);
}

// Round 13
// 320.443 us; speedup vs baseline: 1.1929x; 1.1034x over previous
//
#include <hip/hip_runtime.h>

#define IN_F 256
#define HID1 128
#define HID2 64

typedef __bf16 bf16x8 __attribute__((ext_vector_type(8)));
typedef float f32x4 __attribute__((ext_vector_type(4)));
typedef unsigned short ushort8 __attribute__((ext_vector_type(8)));
typedef unsigned long long u64;

__device__ inline unsigned short f2bf(float f) {
    unsigned int u = __float_as_uint(f);
    u += 0x7fffu + ((u >> 16) & 1u);   // round-to-nearest-even
    return (unsigned short)(u >> 16);
}
__device__ inline float bf2f(unsigned short u) {
    return __uint_as_float(((unsigned int)u) << 16);
}

// ---------------- index-format detection ----------------
__global__ void detect_kernel(const int* __restrict__ e, long long nOdd, int* flag) {
    long long stride = (long long)gridDim.x * blockDim.x;
    for (long long i = (long long)blockIdx.x * blockDim.x + threadIdx.x; i < nOdd; i += stride) {
        if (e[2 * i + 1] != 0) { *flag = 1; return; }
    }
}

__device__ inline int edge_src(const void* e, const int is32, long long i, int E) {
    return is32 ? ((const int*)e)[i] : (int)((const long long*)e)[i];
}
__device__ inline int edge_dst(const void* e, const int is32, long long i, int E) {
    return is32 ? ((const int*)e)[E + i] : (int)((const long long*)e)[E + i];
}

// ---------------- degree count ----------------
__global__ void indeg_kernel(const void* __restrict__ e, const int* __restrict__ flag,
                             int* __restrict__ cnt, int N, int E) {
    const int is32 = *flag;
    long long stride = (long long)gridDim.x * blockDim.x;
    for (long long i = (long long)blockIdx.x * blockDim.x + threadIdx.x; i < E; i += stride) {
        int d = edge_dst(e, is32, i, E);
        if ((unsigned)d < (unsigned)N) atomicAdd(&cnt[d], 1);
    }
}

__global__ void dinv_kernel(const int* __restrict__ cnt, float* __restrict__ dinv, int N) {
    int i = blockIdx.x * blockDim.x + threadIdx.x;
    if (i < N) dinv[i] = rsqrtf((float)(cnt[i] + 1));
}

// ---------------- exclusive scan ----------------
__global__ __launch_bounds__(256) void scan1_kernel(const int* __restrict__ cnt,
                                                    int* __restrict__ excl,
                                                    int* __restrict__ bsum, int N) {
    __shared__ int wsums[4];
    __shared__ int wpre[4];
    const int t = threadIdx.x;
    const int base = blockIdx.x * 2048 + t * 8;
    int v[8];
    int s = 0;
#pragma unroll
    for (int j = 0; j < 8; j++) {
        v[j] = (base + j < N) ? cnt[base + j] : 0;
        s += v[j];
    }
    const int lane = t & 63;
    int x = s;
#pragma unroll
    for (int off = 1; off < 64; off <<= 1) {
        int y = __shfl_up(x, off, 64);
        if (lane >= off) x += y;
    }
    if (lane == 63) wsums[t >> 6] = x;
    __syncthreads();
    if (t == 0) {
        int r = 0;
        for (int w = 0; w < 4; w++) { wpre[w] = r; r += wsums[w]; }
    }
    __syncthreads();
    int run = wpre[t >> 6] + x - s;
#pragma unroll
    for (int j = 0; j < 8; j++) {
        if (base + j < N) excl[base + j] = run;
        run += v[j];
    }
    if (t == 255) bsum[blockIdx.x] = wpre[3] + wsums[3];
}

__global__ void scan2_kernel(int* bsum, int NB) {
    if (threadIdx.x == 0 && blockIdx.x == 0) {
        int r = 0;
        for (int i = 0; i < NB; i++) { int t = bsum[i]; bsum[i] = r; r += t; }
        bsum[NB] = r;
    }
}

__global__ void scan3_kernel(const int* __restrict__ excl, const int* __restrict__ bsum,
                             int* __restrict__ rowptr, int* __restrict__ cursor, int N) {
    int i = blockIdx.x * blockDim.x + threadIdx.x;
    if (i < N) {
        int rp = excl[i] + bsum[i >> 11];
        rowptr[i] = rp;
        cursor[i] = rp;
    } else if (i == N) {
        rowptr[N] = bsum[(N + 2047) >> 11];
    }
}

// ---------------- CSR fill, dst-windowed (write region L2-resident per pass) ----------
__global__ void fill_kernel(const void* __restrict__ e, const int* __restrict__ flag,
                            const float* __restrict__ dinv, int* __restrict__ cursor,
                            u64* __restrict__ cw, int E, int lo, int hi) {
    const int is32 = *flag;
    long long stride = (long long)gridDim.x * blockDim.x;
    for (long long i = (long long)blockIdx.x * blockDim.x + threadIdx.x; i < E; i += stride) {
        int d = edge_dst(e, is32, i, E);
        if (d < lo || d >= hi) continue;
        int s = edge_src(e, is32, i, E);
        if ((unsigned)s >= 0x80000000u) continue;
        int pos = atomicAdd(&cursor[d], 1);
        cw[pos] = ((u64)__float_as_uint(dinv[s]) << 32) | (unsigned int)s;
    }
}

// ---------------- Wt bf16 prep: Wbt[col][k] = bf16(W[k][col]) ----------------
__global__ void wbt_kernel(const float* __restrict__ W, unsigned short* __restrict__ Wbt,
                           int K, int C) {
    int t = blockIdx.x * 256 + threadIdx.x;
    if (t >= K * C) return;
    int c = t / K;
    int k = t - c * K;
    Wbt[t] = f2bf(W[k * C + c]);
}

// ---------------- GEMM1 MFMA: h1b[N,128](bf16) = x[N,256] @ W1[256,128] ----------------
__global__ __launch_bounds__(256) void gemm1_mfma_kernel(const float* __restrict__ x,
                                                         const unsigned short* __restrict__ Wbt,
                                                         unsigned short* __restrict__ hb, int N) {
    __shared__ unsigned short As[64 * 64];    // [row][k] swizzled
    __shared__ unsigned short Bs[128 * 64];   // [col][k] swizzled
    const int t = threadIdx.x;
    const int w = t >> 6;
    const int l = t & 63;
    const int lrow = l & 15;
    const int g = l >> 4;
    const int row0 = blockIdx.x * 64;

    f32x4 acc[4][2];
#pragma unroll
    for (int m = 0; m < 4; m++)
#pragma unroll
        for (int n = 0; n < 2; n++) acc[m][n] = (f32x4){0.f, 0.f, 0.f, 0.f};

    for (int kc = 0; kc < 4; kc++) {
        __syncthreads();
#pragma unroll
        for (int it = 0; it < 2; it++) {
            int slot = it * 256 + t;
            int r = slot >> 3;
            int k0 = (slot & 7) * 8;
            int grow = row0 + r;
            float4 v0 = make_float4(0.f, 0.f, 0.f, 0.f), v1 = v0;
            if (grow < N) {
                const float* p = &x[(long long)grow * IN_F + kc * 64 + k0];
                v0 = *(const float4*)p;
                v1 = *(const float4*)(p + 4);
            }
            ushort8 u;
            u[0] = f2bf(v0.x); u[1] = f2bf(v0.y); u[2] = f2bf(v0.z); u[3] = f2bf(v0.w);
            u[4] = f2bf(v1.x); u[5] = f2bf(v1.y); u[6] = f2bf(v1.z); u[7] = f2bf(v1.w);
            *(ushort8*)&As[r * 64 + (k0 ^ ((r & 7) << 3))] = u;
        }
#pragma unroll
        for (int it = 0; it < 4; it++) {
            int slot = it * 256 + t;
            int c = slot >> 3;
            int k0 = (slot & 7) * 8;
            ushort8 u = *(const ushort8*)&Wbt[c * IN_F + kc * 64 + k0];
            *(ushort8*)&Bs[c * 64 + (k0 ^ ((c & 7) << 3))] = u;
        }
        __syncthreads();
#pragma unroll
        for (int ks = 0; ks < 2; ks++) {
            int kk = ks * 32 + g * 8;
            bf16x8 af[4], bfr[2];
#pragma unroll
            for (int m = 0; m < 4; m++) {
                int r = m * 16 + lrow;
                af[m] = *(bf16x8*)&As[r * 64 + (kk ^ ((r & 7) << 3))];
            }
#pragma unroll
            for (int n = 0; n < 2; n++) {
                int c = w * 32 + n * 16 + lrow;
                bfr[n] = *(bf16x8*)&Bs[c * 64 + (kk ^ ((c & 7) << 3))];
            }
#pragma unroll
            for (int m = 0; m < 4; m++)
#pragma unroll
                for (int n = 0; n < 2; n++)
                    acc[m][n] = __builtin_amdgcn_mfma_f32_16x16x32_bf16(af[m], bfr[n], acc[m][n], 0, 0, 0);
        }
    }
#pragma unroll
    for (int m = 0; m < 4; m++) {
        int rbase = row0 + m * 16 + g * 4;
#pragma unroll
        for (int j = 0; j < 4; j++) {
            int grow = rbase + j;
            if (grow < N) {
#pragma unroll
                for (int n = 0; n < 2; n++)
                    hb[(long long)grow * HID1 + w * 32 + n * 16 + lrow] = f2bf(acc[m][n][j]);
            }
        }
    }
}

// ---------------- GEMM2 MFMA: h2b[N,64](bf16) = agg1b[N,128](bf16) @ W2[128,64] -----------
__global__ __launch_bounds__(256) void gemm2_mfma_kernel(const unsigned short* __restrict__ ab,
                                                         const unsigned short* __restrict__ Wbt,
                                                         unsigned short* __restrict__ hb, int N) {
    __shared__ unsigned short As[64 * 64];    // [row][k] swizzled
    __shared__ unsigned short Bs[64 * 64];    // [col][k] swizzled
    const int t = threadIdx.x;
    const int w = t >> 6;          // wave 0..3 -> cols w*16..+15
    const int l = t & 63;
    const int lrow = l & 15;
    const int g = l >> 4;
    const int row0 = blockIdx.x * 64;

    f32x4 acc[4];
#pragma unroll
    for (int m = 0; m < 4; m++) acc[m] = (f32x4){0.f, 0.f, 0.f, 0.f};

    for (int kc = 0; kc < 2; kc++) {
        __syncthreads();
#pragma unroll
        for (int it = 0; it < 2; it++) {
            int slot = it * 256 + t;
            int r = slot >> 3;
            int k0 = (slot & 7) * 8;
            int grow = row0 + r;
            ushort8 u = (ushort8){0, 0, 0, 0, 0, 0, 0, 0};
            if (grow < N)
                u = *(const ushort8*)&ab[(long long)grow * HID1 + kc * 64 + k0];
            *(ushort8*)&As[r * 64 + (k0 ^ ((r & 7) << 3))] = u;
        }
#pragma unroll
        for (int it = 0; it < 2; it++) {
            int slot = it * 256 + t;
            int c = slot >> 3;
            int k0 = (slot & 7) * 8;
            ushort8 u = *(const ushort8*)&Wbt[c * HID1 + kc * 64 + k0];
            *(ushort8*)&Bs[c * 64 + (k0 ^ ((c & 7) << 3))] = u;
        }
        __syncthreads();
#pragma unroll
        for (int ks = 0; ks < 2; ks++) {
            int kk = ks * 32 + g * 8;
            bf16x8 af[4], bfr;
#pragma unroll
            for (int m = 0; m < 4; m++) {
                int r = m * 16 + lrow;
                af[m] = *(bf16x8*)&As[r * 64 + (kk ^ ((r & 7) << 3))];
            }
            {
                int c = w * 16 + lrow;
                bfr = *(bf16x8*)&Bs[c * 64 + (kk ^ ((c & 7) << 3))];
            }
#pragma unroll
            for (int m = 0; m < 4; m++)
                acc[m] = __builtin_amdgcn_mfma_f32_16x16x32_bf16(af[m], bfr, acc[m], 0, 0, 0);
        }
    }
#pragma unroll
    for (int m = 0; m < 4; m++) {
        int rbase = row0 + m * 16 + g * 4;
#pragma unroll
        for (int j = 0; j < 4; j++) {
            int grow = rbase + j;
            if (grow < N)
                hb[(long long)grow * HID2 + w * 16 + lrow] = f2bf(acc[m][j]);
        }
    }
}

// ---------------- CSR gather (bf16 features, packed u64 edges, 4-wide unroll) -------------
// RELUBF=true: write relu(result) as bf16 (ushort8). false: write f32 (2x float4).
template <int G, bool RELUBF>
__global__ __launch_bounds__(256) void gather_bf16_kernel(const unsigned short* __restrict__ hb,
                                                          const float* __restrict__ bias,
                                                          const float* __restrict__ dinv,
                                                          const int* __restrict__ rowptr,
                                                          const u64* __restrict__ cw,
                                                          void* __restrict__ out, int N) {
    long long tid = (long long)blockIdx.x * 256 + threadIdx.x;
    int node = (int)(tid / G);
    int g = (int)(tid % G);
    if (node >= N) return;
    const ushort8* h8 = (const ushort8*)hb;
    float di = dinv[node];
    ushort8 hv = h8[(long long)node * G + g];
    float sum[8];
#pragma unroll
    for (int j = 0; j < 8; j++) sum[j] = di * bf2f(hv[j]);
    int p0 = rowptr[node], p1 = rowptr[node + 1];
    int p = p0;
    for (; p + 3 < p1; p += 4) {
        u64 c0 = cw[p], c1 = cw[p + 1], c2 = cw[p + 2], c3 = cw[p + 3];
        float w0 = __uint_as_float((unsigned int)(c0 >> 32));
        float w1 = __uint_as_float((unsigned int)(c1 >> 32));
        float w2 = __uint_as_float((unsigned int)(c2 >> 32));
        float w3 = __uint_as_float((unsigned int)(c3 >> 32));
        ushort8 v0 = h8[(long long)(unsigned int)c0 * G + g];
        ushort8 v1 = h8[(long long)(unsigned int)c1 * G + g];
        ushort8 v2 = h8[(long long)(unsigned int)c2 * G + g];
        ushort8 v3 = h8[(long long)(unsigned int)c3 * G + g];
#pragma unroll
        for (int j = 0; j < 8; j++)
            sum[j] += (w0 * bf2f(v0[j]) + w1 * bf2f(v1[j])) +
                      (w2 * bf2f(v2[j]) + w3 * bf2f(v3[j]));
    }
    for (; p < p1; p++) {
        u64 c0 = cw[p];
        float w0 = __uint_as_float((unsigned int)(c0 >> 32));
        ushort8 v0 = h8[(long long)(unsigned int)c0 * G + g];
#pragma unroll
        for (int j = 0; j < 8; j++) sum[j] += w0 * bf2f(v0[j]);
    }
    float4 b0 = ((const float4*)bias)[g * 2];
    float4 b1 = ((const float4*)bias)[g * 2 + 1];
    float r[8];
    r[0] = b0.x + di * sum[0]; r[1] = b0.y + di * sum[1];
    r[2] = b0.z + di * sum[2]; r[3] = b0.w + di * sum[3];
    r[4] = b1.x + di * sum[4]; r[5] = b1.y + di * sum[5];
    r[6] = b1.z + di * sum[6]; r[7] = b1.w + di * sum[7];
    if (RELUBF) {
        ushort8 u;
#pragma unroll
        for (int j = 0; j < 8; j++) u[j] = f2bf(fmaxf(r[j], 0.f));
        ((ushort8*)out)[(long long)node * G + g] = u;
    } else {
        float4 o0 = make_float4(r[0], r[1], r[2], r[3]);
        float4 o1 = make_float4(r[4], r[5], r[6], r[7]);
        float4* op = (float4*)((float*)out + ((long long)node * G + g) * 8);
        op[0] = o0;
        op[1] = o1;
    }
}

extern "C" void kernel_launch(void* const* d_in, const int* in_sizes, int n_in,
                              void* d_out, int out_size, void* d_ws, size_t ws_size,
                              hipStream_t stream) {
    const float* x  = (const float*)d_in[0];
    const void*  ei = d_in[1];
    const float* W1 = (const float*)d_in[2];
    const float* b1 = (const float*)d_in[3];
    const float* W2 = (const float*)d_in[4];
    const float* b2 = (const float*)d_in[5];
    float* out = (float*)d_out;

    const int N = in_sizes[0] / IN_F;          // 100000
    const int E = in_sizes[1] / 2;             // 1600000
    const int NB = (N + 2047) / 2048;

    char* ws = (char*)d_ws;
    size_t off = 0;
    auto alloc = [&](size_t bytes) -> char* {
        char* p = ws + off;
        off = (off + bytes + 255) & ~(size_t)255;
        return p;
    };
    int*   flag   = (int*)alloc(4);
    int*   cnt    = (int*)alloc((size_t)N * 4);
    float* dinv   = (float*)alloc((size_t)N * 4);
    int*   rowptr = (int*)alloc((size_t)(N + 1) * 4);
    int*   cursor = (int*)alloc((size_t)N * 4);
    int*   excl   = (int*)alloc((size_t)N * 4);
    int*   bsum   = (int*)alloc((size_t)(NB + 1) * 4);
    u64*   cw     = (u64*)alloc((size_t)E * 8);
    unsigned short* w1bt  = (unsigned short*)alloc((size_t)HID1 * IN_F * 2);
    unsigned short* w2bt  = (unsigned short*)alloc((size_t)HID2 * HID1 * 2);
    unsigned short* h1b   = (unsigned short*)alloc((size_t)N * HID1 * 2);  // bf16
    unsigned short* agg1b = (unsigned short*)alloc((size_t)N * HID1 * 2);  // bf16 (relu'd)
    unsigned short* h2b   = (unsigned short*)alloc((size_t)N * HID2 * 2);  // bf16

    hipMemsetAsync(flag, 0, sizeof(int), stream);
    hipMemsetAsync(cnt, 0, (size_t)N * 4, stream);

    detect_kernel<<<1024, 256, 0, stream>>>((const int*)ei, (long long)E, flag);
    indeg_kernel<<<2048, 256, 0, stream>>>(ei, flag, cnt, N, E);
    dinv_kernel<<<(N + 255) / 256, 256, 0, stream>>>(cnt, dinv, N);

    scan1_kernel<<<NB, 256, 0, stream>>>(cnt, excl, bsum, N);
    scan2_kernel<<<1, 64, 0, stream>>>(bsum, NB);
    scan3_kernel<<<(N + 256) / 256, 256, 0, stream>>>(excl, bsum, rowptr, cursor, N);

    // dst-windowed fill: 4 passes, each write region L2-resident
    const int W = 4;
    for (int p = 0; p < W; p++) {
        int lo = (int)((long long)N * p / W);
        int hi = (int)((long long)N * (p + 1) / W);
        fill_kernel<<<2048, 256, 0, stream>>>(ei, flag, dinv, cursor, cw, E, lo, hi);
    }

    wbt_kernel<<<(HID1 * IN_F + 255) / 256, 256, 0, stream>>>(W1, w1bt, IN_F, HID1);
    wbt_kernel<<<(HID2 * HID1 + 255) / 256, 256, 0, stream>>>(W2, w2bt, HID1, HID2);

    // Layer 1: MFMA GEMM -> gather (relu+bf16 fused into epilogue)
    gemm1_mfma_kernel<<<(N + 63) / 64, 256, 0, stream>>>(x, w1bt, h1b, N);
    gather_bf16_kernel<16, true><<<(int)(((long long)N * 16 + 255) / 256), 256, 0, stream>>>(
        h1b, b1, dinv, rowptr, cw, agg1b, N);

    // Layer 2: MFMA GEMM (bf16 A) -> gather (f32 out)
    gemm2_mfma_kernel<<<(N + 63) / 64, 256, 0, stream>>>(agg1b, w2bt, h2b, N);
    gather_bf16_kernel<8, false><<<(int)(((long long)N * 8 + 255) / 256), 256, 0, stream>>>(
        h2b, b2, dinv, rowptr, cw, out, N);
}